// Round 3
// baseline (1922.939 us; speedup 1.0000x reference)
//
#include <hip/hip_runtime.h>

#define N_NODES 50000
#define N_EDGES 600000
#define DIM 128
#define NSTAT_BLOCKS 100
#define ROWS_PER_STAT 500   // 100 * 500 = 50000

typedef __attribute__((ext_vector_type(8))) short s16x8;
typedef __attribute__((ext_vector_type(8))) unsigned short u16x8;
typedef __attribute__((ext_vector_type(4))) float f32x4;

__device__ __forceinline__ unsigned short f2b(float f) {
    union { float f; unsigned int i; } v;
    v.f = f;
    unsigned int i = v.i;
    return (unsigned short)((i + 0x7FFFu + ((i >> 16) & 1u)) >> 16);
}

// pack 8 fp32 -> 8 bf16 (RNE; exact if values are already bf16-quantized)
__device__ __forceinline__ s16x8 cvt8(f32x4 a, f32x4 b) {
    union { u16x8 u; s16x8 s; } t;
#pragma unroll
    for (int j = 0; j < 4; j++) { t.u[j] = f2b(a[j]); t.u[4 + j] = f2b(b[j]); }
    return t.s;
}

// ---------------------------------------------------------------------------
// K1: edge scatter. 16 threads/edge, 8 fp32 dims/thread (2x16B loads).
// msg = relu(x[src] + edge_attr); atomicAdd into fp32 agg. Negative message
// adds 0 -> skip the atomic (~50% atomic reduction, exec-mask predicated).
// ---------------------------------------------------------------------------
__global__ __launch_bounds__(256) void k_scatter(
    const float* __restrict__ x,
    const int* __restrict__ ei,
    const float* __restrict__ ea,
    float* __restrict__ agg)
{
    int t = blockIdx.x * 256 + threadIdx.x;
    int e = t >> 4;
    int part = t & 15;
    int src = ei[e];
    int dst = ei[N_EDGES + e];
    const float* xp = x + (size_t)src * DIM + part * 8;
    const float* ep = ea + (size_t)e * DIM + part * 8;
    f32x4 x0 = *(const f32x4*)xp;
    f32x4 x1 = *(const f32x4*)(xp + 4);
    f32x4 e0 = *(const f32x4*)ep;
    f32x4 e1 = *(const f32x4*)(ep + 4);
    float* outp = agg + (size_t)dst * DIM + part * 8;
#pragma unroll
    for (int j = 0; j < 4; j++) {
        float m = x0[j] + e0[j];
        if (m > 0.0f) atomicAdd(outp + j, m);
    }
#pragma unroll
    for (int j = 0; j < 4; j++) {
        float m = x1[j] + e1[j];
        if (m > 0.0f) atomicAdd(outp + 4 + j, m);
    }
}

// ---------------------------------------------------------------------------
// K2: fused  h0 = bf16(x+agg);  h1 = relu(h0@w1^T+b1);  h2 = h1@w2^T+b2 (fp32)
// stored into d_out (BN applied in-place later).
// One wave = 2 row-tiles of 16 (32 rows) x 128 cols, mfma_f32_16x16x32_bf16;
// B-fragment loaded once per (t,q) and shared by both row tiles.
// A-frag: A[m=lane&15][k=32q+8*(lane>>4)+j]; B[k][n=lane&15]=w[n][k]
// (torch Linear weight [out][in] is already B^T layout, contiguous in k).
// C/D: col=lane&15, row=4*(lane>>4)+reg.
// h1 round-trips through padded LDS [32][136] bf16 (2-way aliasing = free).
// No cross-wave sharing -> no __syncthreads.
// ---------------------------------------------------------------------------
__global__ __launch_bounds__(256) void k_mlp(
    const float* __restrict__ x,
    const float* __restrict__ agg,
    const float* __restrict__ w1,
    const float* __restrict__ b1,
    const float* __restrict__ w2,
    const float* __restrict__ b2,
    float* __restrict__ h2out)
{
    __shared__ __align__(16) unsigned short lds[4][32][136];
    const int wave = threadIdx.x >> 6;
    const int lane = threadIdx.x & 63;
    const int n = lane & 15;
    const int g = lane >> 4;
    const int r0 = blockIdx.x * 128 + wave * 32;
    if (r0 >= N_NODES) return;

    // ---- A fragments of h0 = bf16(x + agg), 2 row tiles
    s16x8 afrag[2][4];
#pragma unroll
    for (int tile = 0; tile < 2; tile++) {
        int row = r0 + tile * 16 + n;
        if (row > N_NODES - 1) row = N_NODES - 1;   // tail clamp; stores guarded below
        const float* xr = x + (size_t)row * DIM;
        const float* ar = agg + (size_t)row * DIM;
#pragma unroll
        for (int q = 0; q < 4; q++) {
            int k0 = 32 * q + 8 * g;
            f32x4 s0 = *(const f32x4*)(xr + k0);
            f32x4 s1 = *(const f32x4*)(xr + k0 + 4);
            f32x4 a0 = *(const f32x4*)(ar + k0);
            f32x4 a1 = *(const f32x4*)(ar + k0 + 4);
#pragma unroll
            for (int j = 0; j < 4; j++) { s0[j] += a0[j]; s1[j] += a1[j]; }
            afrag[tile][q] = cvt8(s0, s1);
        }
    }

    // ---- GEMM1 + bias + relu -> h1 (bf16) into LDS
#pragma unroll
    for (int t = 0; t < 8; t++) {
        f32x4 c0 = {0.f, 0.f, 0.f, 0.f};
        f32x4 c1 = {0.f, 0.f, 0.f, 0.f};
#pragma unroll
        for (int q = 0; q < 4; q++) {
            const float* wr = w1 + (16 * t + n) * DIM + 32 * q + 8 * g;
            s16x8 bfr = cvt8(*(const f32x4*)wr, *(const f32x4*)(wr + 4));
            c0 = __builtin_amdgcn_mfma_f32_16x16x32_bf16(afrag[0][q], bfr, c0, 0, 0, 0);
            c1 = __builtin_amdgcn_mfma_f32_16x16x32_bf16(afrag[1][q], bfr, c1, 0, 0, 0);
        }
        float bias = b1[16 * t + n];
#pragma unroll
        for (int rr = 0; rr < 4; rr++) {
            lds[wave][4 * g + rr][16 * t + n]      = f2b(fmaxf(c0[rr] + bias, 0.f));
            lds[wave][16 + 4 * g + rr][16 * t + n] = f2b(fmaxf(c1[rr] + bias, 0.f));
        }
    }

    // ---- A fragments of h1 from LDS
    s16x8 a2[2][4];
#pragma unroll
    for (int tile = 0; tile < 2; tile++) {
#pragma unroll
        for (int q = 0; q < 4; q++) {
            union { u16x8 u; s16x8 s; } tmp;
            tmp.u = *(const u16x8*)&lds[wave][tile * 16 + n][32 * q + 8 * g];
            a2[tile][q] = tmp.s;
        }
    }

    // ---- GEMM2 + bias -> h2 fp32, direct scattered store (64B runs, L2 merges)
#pragma unroll
    for (int t = 0; t < 8; t++) {
        f32x4 c0 = {0.f, 0.f, 0.f, 0.f};
        f32x4 c1 = {0.f, 0.f, 0.f, 0.f};
#pragma unroll
        for (int q = 0; q < 4; q++) {
            const float* wr = w2 + (16 * t + n) * DIM + 32 * q + 8 * g;
            s16x8 bfr = cvt8(*(const f32x4*)wr, *(const f32x4*)(wr + 4));
            c0 = __builtin_amdgcn_mfma_f32_16x16x32_bf16(a2[0][q], bfr, c0, 0, 0, 0);
            c1 = __builtin_amdgcn_mfma_f32_16x16x32_bf16(a2[1][q], bfr, c1, 0, 0, 0);
        }
        float bias = b2[16 * t + n];
#pragma unroll
        for (int rr = 0; rr < 4; rr++) {
            int row0 = r0 + 4 * g + rr;
            int row1 = r0 + 16 + 4 * g + rr;
            if (row0 < N_NODES) h2out[(size_t)row0 * DIM + 16 * t + n] = c0[rr] + bias;
            if (row1 < N_NODES) h2out[(size_t)row1 * DIM + 16 * t + n] = c1[rr] + bias;
        }
    }
}

// ---------------------------------------------------------------------------
// K2b: per-block column sums/sumsq of h2 (fp32) -> fp32 partials (no atomics)
// Block = 256 threads = 16 row-lanes x 16 col-groups (8 cols each).
// ---------------------------------------------------------------------------
__global__ __launch_bounds__(256) void k_colstats(
    const float* __restrict__ h2,
    float* __restrict__ psum, float* __restrict__ psumsq)
{
    __shared__ float lsum[4][16][8];
    __shared__ float lss[4][16][8];
    const int t = threadIdx.x;
    const int wave = t >> 6;
    const int lane = t & 63;
    const int colg = lane & 15;
    const int rowLane = t >> 4;
    const int base = blockIdx.x * ROWS_PER_STAT;

    float s[8], ss[8];
#pragma unroll
    for (int j = 0; j < 8; j++) { s[j] = 0.f; ss[j] = 0.f; }

    for (int r = base + rowLane; r < base + ROWS_PER_STAT; r += 16) {
        const float* p = h2 + (size_t)r * DIM + colg * 8;
        f32x4 v0 = *(const f32x4*)p;
        f32x4 v1 = *(const f32x4*)(p + 4);
#pragma unroll
        for (int j = 0; j < 4; j++) {
            s[j] += v0[j];      ss[j] += v0[j] * v0[j];
            s[4 + j] += v1[j];  ss[4 + j] += v1[j] * v1[j];
        }
    }
#pragma unroll
    for (int j = 0; j < 8; j++) {
        s[j]  += __shfl_xor(s[j], 16);  s[j]  += __shfl_xor(s[j], 32);
        ss[j] += __shfl_xor(ss[j], 16); ss[j] += __shfl_xor(ss[j], 32);
    }
    if (lane < 16) {
#pragma unroll
        for (int j = 0; j < 8; j++) { lsum[wave][lane][j] = s[j]; lss[wave][lane][j] = ss[j]; }
    }
    __syncthreads();
    if (t < DIM) {
        int cg = t >> 3, j = t & 7;
        float a = lsum[0][cg][j] + lsum[1][cg][j] + lsum[2][cg][j] + lsum[3][cg][j];
        float b = lss[0][cg][j]  + lss[1][cg][j]  + lss[2][cg][j]  + lss[3][cg][j];
        psum[blockIdx.x * DIM + t]   = a;
        psumsq[blockIdx.x * DIM + t] = b;
    }
}

// ---------------------------------------------------------------------------
// K3: BN finalize: sum partials, compute per-column scale/shift (1 block)
// ---------------------------------------------------------------------------
__global__ void k_bn_finalize(
    const float* __restrict__ psum, const float* __restrict__ psumsq,
    const float* __restrict__ bnw, const float* __restrict__ bnb,
    float* __restrict__ scale, float* __restrict__ shiftv)
{
    int c = threadIdx.x;
    float s = 0.f, ss = 0.f;
    for (int b = 0; b < NSTAT_BLOCKS; b++) {
        s  += psum[b * DIM + c];
        ss += psumsq[b * DIM + c];
    }
    const float invN = 1.0f / (float)N_NODES;
    float mean = s * invN;
    float var = ss * invN - mean * mean;
    var = fmaxf(var, 0.0f);
    float sc = bnw[c] * rsqrtf(var + 1e-5f);
    scale[c] = sc;
    shiftv[c] = bnb[c] - mean * sc;
}

// ---------------------------------------------------------------------------
// K4: out = relu(h2*scale + shift), fp32 in place on d_out, 8 elems/thread
// ---------------------------------------------------------------------------
__global__ __launch_bounds__(256) void k_bn_apply(
    float* __restrict__ h2,
    const float* __restrict__ scale, const float* __restrict__ shiftv)
{
    int t = blockIdx.x * 256 + threadIdx.x;
    int col0 = (t * 8) & (DIM - 1);
    float* p = h2 + (size_t)t * 8;
    f32x4 h0 = *(const f32x4*)p;
    f32x4 h1 = *(const f32x4*)(p + 4);
    f32x4 s0 = *(const f32x4*)(scale + col0);
    f32x4 s1 = *(const f32x4*)(scale + col0 + 4);
    f32x4 f0 = *(const f32x4*)(shiftv + col0);
    f32x4 f1 = *(const f32x4*)(shiftv + col0 + 4);
    f32x4 o0, o1;
#pragma unroll
    for (int j = 0; j < 4; j++) {
        o0[j] = fmaxf(fmaf(h0[j], s0[j], f0[j]), 0.0f);
        o1[j] = fmaxf(fmaf(h1[j], s1[j], f1[j]), 0.0f);
    }
    *(f32x4*)p = o0;
    *(f32x4*)(p + 4) = o1;
}

// ---------------------------------------------------------------------------
// Workspace budget: exactly 25,600,000 bytes (one fp32 [N, DIM] buffer).
//   Phase A (K1,K2):   agg fp32 [50000][128]   = ws[0, 25.6e6)
//   Phase B (K2b..K4): psum fp32 [100][128]    = ws[0,      51200)
//                      psumsq fp32 [100][128]  = ws[51200, 102400)
//                      scale fp32 [128]        = ws[102400, 102912)
//                      shift fp32 [128]        = ws[102912, 103424)
//   h2 lives in d_out (fp32); K4 applies BN+relu in place.
// ---------------------------------------------------------------------------
extern "C" void kernel_launch(void* const* d_in, const int* in_sizes, int n_in,
                              void* d_out, int out_size, void* d_ws, size_t ws_size,
                              hipStream_t stream) {
    const float* x   = (const float*)d_in[0];
    const int*   ei  = (const int*)d_in[1];
    const float* ea  = (const float*)d_in[2];
    const float* w1  = (const float*)d_in[3];
    const float* b1  = (const float*)d_in[4];
    const float* w2  = (const float*)d_in[5];
    const float* b2  = (const float*)d_in[6];
    const float* bnw = (const float*)d_in[7];
    const float* bnb = (const float*)d_in[8];

    char* ws = (char*)d_ws;
    float* agg     = (float*)ws;
    float* psum    = (float*)ws;
    float* psumsq  = (float*)(ws + 51200);
    float* scale   = (float*)(ws + 102400);
    float* shiftv  = (float*)(ws + 102912);
    float* h2      = (float*)d_out;

    // zero agg (ws is poisoned 0xAA before every launch)
    hipMemsetAsync(ws, 0, (size_t)N_NODES * DIM * 4, stream);

    k_scatter<<<N_EDGES * 16 / 256, 256, 0, stream>>>(x, ei, ea, agg);
    k_mlp<<<(N_NODES + 127) / 128, 256, 0, stream>>>(x, agg, w1, b1, w2, b2, h2);
    k_colstats<<<NSTAT_BLOCKS, 256, 0, stream>>>(h2, psum, psumsq);
    k_bn_finalize<<<1, DIM, 0, stream>>>(psum, psumsq, bnw, bnb, scale, shiftv);
    k_bn_apply<<<N_NODES * DIM / 8 / 256, 256, 0, stream>>>(h2, scale, shiftv);
}

// Round 4
// 708.016 us; speedup vs baseline: 2.7160x; 2.7160x over previous
//
#include <hip/hip_runtime.h>

#define N_NODES 50000
#define N_EDGES 600000
#define DIM 128
#define NSTAT_BLOCKS 100
#define ROWS_PER_STAT 500   // 100 * 500 = 50000

typedef __attribute__((ext_vector_type(8))) short s16x8;
typedef __attribute__((ext_vector_type(8))) unsigned short u16x8;
typedef __attribute__((ext_vector_type(4))) float f32x4;
typedef __attribute__((ext_vector_type(2))) float f32x2;

__device__ __forceinline__ unsigned short f2b(float f) {
    union { float f; unsigned int i; } v;
    v.f = f;
    unsigned int i = v.i;
    return (unsigned short)((i + 0x7FFFu + ((i >> 16) & 1u)) >> 16);
}

// pack 8 fp32 -> 8 bf16 (RNE)
__device__ __forceinline__ s16x8 cvt8(f32x4 a, f32x4 b) {
    union { u16x8 u; s16x8 s; } t;
#pragma unroll
    for (int j = 0; j < 4; j++) { t.u[j] = f2b(a[j]); t.u[4 + j] = f2b(b[j]); }
    return t.s;
}

// ---------------------------------------------------------------------------
// Phase A: build CSR by destination, then gather-reduce (NO per-element
// global atomics — round-3 profile showed 38.4M memory-side atomic RMWs
// = 1.17 GB of random 32B HBM writes = 1512 us).
// CSR scratch lives in d_out (dead until k_mlp overwrites it with h2).
// ---------------------------------------------------------------------------

// K0a: histogram of destinations (count lives in the cursor region, zeroed)
__global__ __launch_bounds__(256) void k_hist(
    const int* __restrict__ ei, int* __restrict__ count)
{
    int t = blockIdx.x * 256 + threadIdx.x;
    if (t < N_EDGES) atomicAdd(&count[ei[N_EDGES + t]], 1);
}

// K0b: exclusive scan of counts -> off[0..N]; cursor[v] initialized to off[v].
// cnt_cur is the SAME buffer for input counts and output cursors (in-place,
// safe: each thread reads count[v] before overwriting it).
__global__ __launch_bounds__(1024) void k_scan(
    int* __restrict__ off, int* cnt_cur)
{
    __shared__ int part[1024];
    const int CH = (N_NODES + 1023) / 1024;  // 49
    const int t = threadIdx.x;
    const int lo = t * CH;
    const int hi = (lo + CH < N_NODES) ? lo + CH : N_NODES;
    int s = 0;
    for (int v = lo; v < hi; v++) s += cnt_cur[v];
    part[t] = s;
    __syncthreads();
    for (int d = 1; d < 1024; d <<= 1) {
        int val = (t >= d) ? part[t - d] : 0;
        __syncthreads();
        part[t] += val;
        __syncthreads();
    }
    int run = (t == 0) ? 0 : part[t - 1];
    for (int v = lo; v < hi; v++) {
        int c = cnt_cur[v];
        off[v] = run;
        cnt_cur[v] = run;
        run += c;
    }
    if (t == 0) off[N_NODES] = N_EDGES;
}

// K0c: place edge ids into CSR slots
__global__ __launch_bounds__(256) void k_scatter_ids(
    const int* __restrict__ ei, int* __restrict__ cursor,
    int* __restrict__ sorted_eid)
{
    int t = blockIdx.x * 256 + threadIdx.x;
    if (t < N_EDGES) {
        int pos = atomicAdd(&cursor[ei[N_EDGES + t]], 1);
        sorted_eid[pos] = t;
    }
}

// K1: gather-reduce. One wave per node; lane covers 2 dims. Edge ids/srcs
// preloaded 64-at-a-time into lanes, broadcast via __shfl. One coalesced
// 512B row store per node, no atomics.
__global__ __launch_bounds__(256) void k_gather(
    const float* __restrict__ x,
    const int* __restrict__ ei,
    const float* __restrict__ ea,
    const int* __restrict__ off,
    const int* __restrict__ sorted_eid,
    float* __restrict__ agg)
{
    const int wave = threadIdx.x >> 6;
    const int lane = threadIdx.x & 63;
    const int v = blockIdx.x * 4 + wave;
    if (v >= N_NODES) return;
    const int o0 = off[v], o1 = off[v + 1];
    float a0 = 0.f, a1 = 0.f;
    for (int done = o0; done < o1; done += 64) {
        int cnt = o1 - done; if (cnt > 64) cnt = 64;
        int eid = 0, srcl = 0;
        if (lane < cnt) {
            eid = sorted_eid[done + lane];
            srcl = ei[eid];
        }
        for (int i = 0; i < cnt; i++) {
            int e = __shfl(eid, i);
            int s = __shfl(srcl, i);
            f32x2 xv = *(const f32x2*)(x + (size_t)s * DIM + 2 * lane);
            f32x2 ev = *(const f32x2*)(ea + (size_t)e * DIM + 2 * lane);
            a0 += fmaxf(xv[0] + ev[0], 0.f);
            a1 += fmaxf(xv[1] + ev[1], 0.f);
        }
    }
    f32x2 out; out[0] = a0; out[1] = a1;
    *(f32x2*)(agg + (size_t)v * DIM + 2 * lane) = out;
}

// ---------------------------------------------------------------------------
// K2: fused  h0 = bf16(x+agg);  h1 = relu(h0@w1^T+b1);  h2 = h1@w2^T+b2 (fp32)
// stored into d_out. One wave = 32 rows x 128 cols, mfma_f32_16x16x32_bf16.
// ---------------------------------------------------------------------------
__global__ __launch_bounds__(256) void k_mlp(
    const float* __restrict__ x,
    const float* __restrict__ agg,
    const float* __restrict__ w1,
    const float* __restrict__ b1,
    const float* __restrict__ w2,
    const float* __restrict__ b2,
    float* __restrict__ h2out)
{
    __shared__ __align__(16) unsigned short lds[4][32][136];
    const int wave = threadIdx.x >> 6;
    const int lane = threadIdx.x & 63;
    const int n = lane & 15;
    const int g = lane >> 4;
    const int r0 = blockIdx.x * 128 + wave * 32;
    if (r0 >= N_NODES) return;

    s16x8 afrag[2][4];
#pragma unroll
    for (int tile = 0; tile < 2; tile++) {
        int row = r0 + tile * 16 + n;
        if (row > N_NODES - 1) row = N_NODES - 1;
        const float* xr = x + (size_t)row * DIM;
        const float* ar = agg + (size_t)row * DIM;
#pragma unroll
        for (int q = 0; q < 4; q++) {
            int k0 = 32 * q + 8 * g;
            f32x4 s0 = *(const f32x4*)(xr + k0);
            f32x4 s1 = *(const f32x4*)(xr + k0 + 4);
            f32x4 a0 = *(const f32x4*)(ar + k0);
            f32x4 a1 = *(const f32x4*)(ar + k0 + 4);
#pragma unroll
            for (int j = 0; j < 4; j++) { s0[j] += a0[j]; s1[j] += a1[j]; }
            afrag[tile][q] = cvt8(s0, s1);
        }
    }

#pragma unroll
    for (int t = 0; t < 8; t++) {
        f32x4 c0 = {0.f, 0.f, 0.f, 0.f};
        f32x4 c1 = {0.f, 0.f, 0.f, 0.f};
#pragma unroll
        for (int q = 0; q < 4; q++) {
            const float* wr = w1 + (16 * t + n) * DIM + 32 * q + 8 * g;
            s16x8 bfr = cvt8(*(const f32x4*)wr, *(const f32x4*)(wr + 4));
            c0 = __builtin_amdgcn_mfma_f32_16x16x32_bf16(afrag[0][q], bfr, c0, 0, 0, 0);
            c1 = __builtin_amdgcn_mfma_f32_16x16x32_bf16(afrag[1][q], bfr, c1, 0, 0, 0);
        }
        float bias = b1[16 * t + n];
#pragma unroll
        for (int rr = 0; rr < 4; rr++) {
            lds[wave][4 * g + rr][16 * t + n]      = f2b(fmaxf(c0[rr] + bias, 0.f));
            lds[wave][16 + 4 * g + rr][16 * t + n] = f2b(fmaxf(c1[rr] + bias, 0.f));
        }
    }

    s16x8 a2[2][4];
#pragma unroll
    for (int tile = 0; tile < 2; tile++) {
#pragma unroll
        for (int q = 0; q < 4; q++) {
            union { u16x8 u; s16x8 s; } tmp;
            tmp.u = *(const u16x8*)&lds[wave][tile * 16 + n][32 * q + 8 * g];
            a2[tile][q] = tmp.s;
        }
    }

#pragma unroll
    for (int t = 0; t < 8; t++) {
        f32x4 c0 = {0.f, 0.f, 0.f, 0.f};
        f32x4 c1 = {0.f, 0.f, 0.f, 0.f};
#pragma unroll
        for (int q = 0; q < 4; q++) {
            const float* wr = w2 + (16 * t + n) * DIM + 32 * q + 8 * g;
            s16x8 bfr = cvt8(*(const f32x4*)wr, *(const f32x4*)(wr + 4));
            c0 = __builtin_amdgcn_mfma_f32_16x16x32_bf16(a2[0][q], bfr, c0, 0, 0, 0);
            c1 = __builtin_amdgcn_mfma_f32_16x16x32_bf16(a2[1][q], bfr, c1, 0, 0, 0);
        }
        float bias = b2[16 * t + n];
#pragma unroll
        for (int rr = 0; rr < 4; rr++) {
            int row0 = r0 + 4 * g + rr;
            int row1 = r0 + 16 + 4 * g + rr;
            if (row0 < N_NODES) h2out[(size_t)row0 * DIM + 16 * t + n] = c0[rr] + bias;
            if (row1 < N_NODES) h2out[(size_t)row1 * DIM + 16 * t + n] = c1[rr] + bias;
        }
    }
}

// ---------------------------------------------------------------------------
// K2b: per-block column sums/sumsq of h2 (fp32) -> fp32 partials (no atomics)
// ---------------------------------------------------------------------------
__global__ __launch_bounds__(256) void k_colstats(
    const float* __restrict__ h2,
    float* __restrict__ psum, float* __restrict__ psumsq)
{
    __shared__ float lsum[4][16][8];
    __shared__ float lss[4][16][8];
    const int t = threadIdx.x;
    const int wave = t >> 6;
    const int lane = t & 63;
    const int colg = lane & 15;
    const int rowLane = t >> 4;
    const int base = blockIdx.x * ROWS_PER_STAT;

    float s[8], ss[8];
#pragma unroll
    for (int j = 0; j < 8; j++) { s[j] = 0.f; ss[j] = 0.f; }

    for (int r = base + rowLane; r < base + ROWS_PER_STAT; r += 16) {
        const float* p = h2 + (size_t)r * DIM + colg * 8;
        f32x4 v0 = *(const f32x4*)p;
        f32x4 v1 = *(const f32x4*)(p + 4);
#pragma unroll
        for (int j = 0; j < 4; j++) {
            s[j] += v0[j];      ss[j] += v0[j] * v0[j];
            s[4 + j] += v1[j];  ss[4 + j] += v1[j] * v1[j];
        }
    }
#pragma unroll
    for (int j = 0; j < 8; j++) {
        s[j]  += __shfl_xor(s[j], 16);  s[j]  += __shfl_xor(s[j], 32);
        ss[j] += __shfl_xor(ss[j], 16); ss[j] += __shfl_xor(ss[j], 32);
    }
    if (lane < 16) {
#pragma unroll
        for (int j = 0; j < 8; j++) { lsum[wave][lane][j] = s[j]; lss[wave][lane][j] = ss[j]; }
    }
    __syncthreads();
    if (t < DIM) {
        int cg = t >> 3, j = t & 7;
        float a = lsum[0][cg][j] + lsum[1][cg][j] + lsum[2][cg][j] + lsum[3][cg][j];
        float b = lss[0][cg][j]  + lss[1][cg][j]  + lss[2][cg][j]  + lss[3][cg][j];
        psum[blockIdx.x * DIM + t]   = a;
        psumsq[blockIdx.x * DIM + t] = b;
    }
}

// ---------------------------------------------------------------------------
// K3: BN finalize
// ---------------------------------------------------------------------------
__global__ void k_bn_finalize(
    const float* __restrict__ psum, const float* __restrict__ psumsq,
    const float* __restrict__ bnw, const float* __restrict__ bnb,
    float* __restrict__ scale, float* __restrict__ shiftv)
{
    int c = threadIdx.x;
    float s = 0.f, ss = 0.f;
    for (int b = 0; b < NSTAT_BLOCKS; b++) {
        s  += psum[b * DIM + c];
        ss += psumsq[b * DIM + c];
    }
    const float invN = 1.0f / (float)N_NODES;
    float mean = s * invN;
    float var = ss * invN - mean * mean;
    var = fmaxf(var, 0.0f);
    float sc = bnw[c] * rsqrtf(var + 1e-5f);
    scale[c] = sc;
    shiftv[c] = bnb[c] - mean * sc;
}

// ---------------------------------------------------------------------------
// K4: out = relu(h2*scale + shift), fp32 in place on d_out
// ---------------------------------------------------------------------------
__global__ __launch_bounds__(256) void k_bn_apply(
    float* __restrict__ h2,
    const float* __restrict__ scale, const float* __restrict__ shiftv)
{
    int t = blockIdx.x * 256 + threadIdx.x;
    int col0 = (t * 8) & (DIM - 1);
    float* p = h2 + (size_t)t * 8;
    f32x4 h0 = *(const f32x4*)p;
    f32x4 h1 = *(const f32x4*)(p + 4);
    f32x4 s0 = *(const f32x4*)(scale + col0);
    f32x4 s1 = *(const f32x4*)(scale + col0 + 4);
    f32x4 f0 = *(const f32x4*)(shiftv + col0);
    f32x4 f1 = *(const f32x4*)(shiftv + col0 + 4);
    f32x4 o0, o1;
#pragma unroll
    for (int j = 0; j < 4; j++) {
        o0[j] = fmaxf(fmaf(h0[j], s0[j], f0[j]), 0.0f);
        o1[j] = fmaxf(fmaf(h1[j], s1[j], f1[j]), 0.0f);
    }
    *(f32x4*)p = o0;
    *(f32x4*)(p + 4) = o1;
}

// ---------------------------------------------------------------------------
// Buffers:
//   ws (25.6 MB): agg fp32[50000][128]; phase B reuses front for
//                 psum/psumsq/scale/shift as before.
//   d_out (25.6 MB): phase A = CSR scratch:
//       off     int[50001]  @ byte 0        (200,004 B)
//       cursor  int[50000]  @ byte 200,064  (= count during hist)
//       sorted  int[600000] @ byte 400,128  (2.4 MB)
//     then k_mlp overwrites d_out entirely with h2; K4 applies BN in place.
// ---------------------------------------------------------------------------
extern "C" void kernel_launch(void* const* d_in, const int* in_sizes, int n_in,
                              void* d_out, int out_size, void* d_ws, size_t ws_size,
                              hipStream_t stream) {
    const float* x   = (const float*)d_in[0];
    const int*   ei  = (const int*)d_in[1];
    const float* ea  = (const float*)d_in[2];
    const float* w1  = (const float*)d_in[3];
    const float* b1  = (const float*)d_in[4];
    const float* w2  = (const float*)d_in[5];
    const float* b2  = (const float*)d_in[6];
    const float* bnw = (const float*)d_in[7];
    const float* bnb = (const float*)d_in[8];

    char* ws = (char*)d_ws;
    float* agg     = (float*)ws;
    float* psum    = (float*)ws;
    float* psumsq  = (float*)(ws + 51200);
    float* scale   = (float*)(ws + 102400);
    float* shiftv  = (float*)(ws + 102912);
    float* h2      = (float*)d_out;

    char* ob = (char*)d_out;
    int* off    = (int*)ob;
    int* cursor = (int*)(ob + 200064);   // doubles as count[] during k_hist
    int* sorted = (int*)(ob + 400128);

    // zero off+count regions only (400 KB)
    hipMemsetAsync(d_out, 0, 400128, stream);

    k_hist<<<(N_EDGES + 255) / 256, 256, 0, stream>>>(ei, cursor);
    k_scan<<<1, 1024, 0, stream>>>(off, cursor);
    k_scatter_ids<<<(N_EDGES + 255) / 256, 256, 0, stream>>>(ei, cursor, sorted);
    k_gather<<<(N_NODES + 3) / 4, 256, 0, stream>>>(x, ei, ea, off, sorted, agg);
    k_mlp<<<(N_NODES + 127) / 128, 256, 0, stream>>>(x, agg, w1, b1, w2, b2, h2);
    k_colstats<<<NSTAT_BLOCKS, 256, 0, stream>>>(h2, psum, psumsq);
    k_bn_finalize<<<1, DIM, 0, stream>>>(psum, psumsq, bnw, bnb, scale, shiftv);
    k_bn_apply<<<N_NODES * DIM / 8 / 256, 256, 0, stream>>>(h2, scale, shiftv);
}